// Round 1
// baseline (703.894 us; speedup 1.0000x reference)
//
#include <hip/hip_runtime.h>
#include <hip/hip_bf16.h>
#include <stdint.h>

typedef __bf16 bf16_t;
typedef __bf16 bf16x8 __attribute__((ext_vector_type(8)));
typedef __bf16 bf16x4 __attribute__((ext_vector_type(4)));
typedef float f32x4 __attribute__((ext_vector_type(4)));

// Problem constants (fixed by reference): B=32, H=W=64, C=256, heads=8, ws=8, ss=4
#define MROWS 131072   // B * 64 * 64 tokens (window layout rows)

__device__ __forceinline__ bf16_t to_bf16(float f) {
  __hip_bfloat16 h = __float2bfloat16(f);   // RNE
  return *reinterpret_cast<bf16_t*>(&h);
}

__device__ __forceinline__ f32x4 mfma16(bf16x8 a, bf16x8 b, f32x4 c) {
  return __builtin_amdgcn_mfma_f32_16x16x32_bf16(a, b, c, 0, 0, 0);
}

__device__ __forceinline__ void gload16(const void* g, void* l) {
  __builtin_amdgcn_global_load_lds(
      (const __attribute__((address_space(1))) void*)g,
      (__attribute__((address_space(3))) void*)l, 16, 0, 0);
}

// window-layout row m  ->  x row (this is both the shift+partition gather for LN1
// and the reverse+unshift scatter for the proj epilogue: same bijection)
__device__ __forceinline__ int map_row(int m) {
  int b   = m >> 12;        // / 4096
  int rem = m & 4095;
  int win = rem >> 6;       // 0..63 within image
  int n   = rem & 63;       // token within window
  int gh  = ((win >> 3) << 3) + (n >> 3);
  int gw  = ((win & 7) << 3) + (n & 7);
  int sh  = (gh + 4) & 63;  // shifted source/dest position
  int sw  = (gw + 4) & 63;
  return (b << 12) + (sh << 6) + sw;
}

__device__ __forceinline__ int regid(int g) { return (g < 56) ? 0 : (g < 60 ? 1 : 2); }

// ---------------- fp32 -> bf16 weight convert ----------------
__global__ __launch_bounds__(256) void cvt_kernel(const float* __restrict__ in,
                                                  bf16_t* __restrict__ out, int n) {
  int i = blockIdx.x * 256 + threadIdx.x;
  if (i < n) out[i] = to_bf16(in[i]);
}

// ---------------- LayerNorm (wave per row), optional row-permuted gather ----------------
template <bool PERM>
__global__ __launch_bounds__(256) void ln_kernel(const float* __restrict__ xin,
                                                 const float* __restrict__ g,
                                                 const float* __restrict__ b,
                                                 bf16_t* __restrict__ out) {
  int row  = (blockIdx.x << 2) + (threadIdx.x >> 6);
  int lane = threadIdx.x & 63;
  int src  = PERM ? map_row(row) : row;
  float4 v = *reinterpret_cast<const float4*>(xin + (size_t)src * 256 + (lane << 2));
  float s = v.x + v.y + v.z + v.w;
#pragma unroll
  for (int d = 1; d < 64; d <<= 1) s += __shfl_xor(s, d);
  float mean = s * 0.00390625f;
  float ax = v.x - mean, ay = v.y - mean, az = v.z - mean, aw = v.w - mean;
  float s2 = ax * ax + ay * ay + az * az + aw * aw;
#pragma unroll
  for (int d = 1; d < 64; d <<= 1) s2 += __shfl_xor(s2, d);
  float rstd = rsqrtf(s2 * 0.00390625f + 1e-5f);
  float4 gv = *reinterpret_cast<const float4*>(g + (lane << 2));
  float4 bv = *reinterpret_cast<const float4*>(b + (lane << 2));
  bf16x4 o4;
  o4[0] = to_bf16(ax * rstd * gv.x + bv.x);
  o4[1] = to_bf16(ay * rstd * gv.y + bv.y);
  o4[2] = to_bf16(az * rstd * gv.z + bv.z);
  o4[3] = to_bf16(aw * rstd * gv.w + bv.w);
  *reinterpret_cast<bf16x4*>(out + (size_t)row * 256 + (lane << 2)) = o4;
}

// ---------------- bf16 GEMM, B^T weights (m97 structure): out[m,n] = sum_k A[m,k]*W[n,k] + bias[n]
// EPI 0: store bf16     EPI 1: GELU(exact) then bf16
// EPI 2: fp32 store to permuted row with residual from resid[]   EPI 3: fp32 in-place +=
template <int EPI>
__global__ __launch_bounds__(256) void gemm_bt(const bf16_t* __restrict__ A,
                                               const bf16_t* __restrict__ W,
                                               const float* __restrict__ bias,
                                               void* __restrict__ outp,
                                               const float* __restrict__ resid,
                                               int M, int N, int K) {
  __shared__ __align__(16) bf16_t As[128 * 32];
  __shared__ __align__(16) bf16_t Bs[128 * 32];
  const int tid  = threadIdx.x;
  const int lane = tid & 63, lo = lane & 15, hi = lane >> 4;
  const int wave = tid >> 6;
  const int bm = blockIdx.x << 7, bn = blockIdx.y << 7;
  const int wr = (wave >> 1) << 6, wc = (wave & 1) << 6;
  f32x4 acc[4][4] = {};

  for (int k0 = 0; k0 < K; k0 += 32) {
    __syncthreads();
#pragma unroll
    for (int it = 0; it < 2; ++it) {
      int ch = (it << 8) + tid;           // 512 chunks of 16B per tile
      int r = ch >> 2, kf = (ch & 3) << 3;
      gload16(A + (size_t)(bm + r) * K + (k0 + kf), &As[ch << 3]);
      gload16(W + (size_t)(bn + r) * K + (k0 + kf), &Bs[ch << 3]);
    }
    __syncthreads();
    bf16x8 af[4], bfr[4];
#pragma unroll
    for (int i = 0; i < 4; ++i)
      af[i] = *reinterpret_cast<const bf16x8*>(&As[(wr + (i << 4) + lo) * 32 + (hi << 3)]);
#pragma unroll
    for (int j = 0; j < 4; ++j)
      bfr[j] = *reinterpret_cast<const bf16x8*>(&Bs[(wc + (j << 4) + lo) * 32 + (hi << 3)]);
#pragma unroll
    for (int i = 0; i < 4; ++i)
#pragma unroll
      for (int j = 0; j < 4; ++j)
        acc[i][j] = mfma16(af[i], bfr[j], acc[i][j]);
  }

  float bv[4];
#pragma unroll
  for (int j = 0; j < 4; ++j) bv[j] = bias[bn + wc + (j << 4) + lo];

#pragma unroll
  for (int i = 0; i < 4; ++i) {
#pragma unroll
    for (int r = 0; r < 4; ++r) {
      int row = bm + wr + (i << 4) + (hi << 2) + r;
      if constexpr (EPI == 2) {
        int xr = map_row(row);
        float* o = (float*)outp;
#pragma unroll
        for (int j = 0; j < 4; ++j) {
          int col = bn + wc + (j << 4) + lo;
          size_t idx = (size_t)xr * 256 + col;
          o[idx] = resid[idx] + acc[i][j][r] + bv[j];
        }
      } else if constexpr (EPI == 3) {
        float* o = (float*)outp;
#pragma unroll
        for (int j = 0; j < 4; ++j) {
          int col = bn + wc + (j << 4) + lo;
          size_t idx = (size_t)row * 256 + col;
          o[idx] = o[idx] + acc[i][j][r] + bv[j];
        }
      } else {
        bf16_t* o = (bf16_t*)outp;
#pragma unroll
        for (int j = 0; j < 4; ++j) {
          int col = bn + wc + (j << 4) + lo;
          float v = acc[i][j][r] + bv[j];
          if constexpr (EPI == 1) v = 0.5f * v * (1.0f + erff(v * 0.70710678118654752f));
          o[(size_t)row * N + col] = to_bf16(v);
        }
      }
    }
  }
}

// ---------------- windowed attention: one wave per (window, head) ----------------
// q,k,v: [131072, 256] bf16 each (row = win*64 + token, col = head*32 + d)
__global__ __launch_bounds__(256) void attn_kernel(const bf16_t* __restrict__ q,
                                                   const bf16_t* __restrict__ k,
                                                   const bf16_t* __restrict__ v,
                                                   const float* __restrict__ rpbt,
                                                   bf16_t* __restrict__ o) {
  __shared__ __align__(16) bf16_t Pl[4][64 * 72];
  __shared__ __align__(16) bf16_t Vt[4][32 * 72];
  const int wave = threadIdx.x >> 6, lane = threadIdx.x & 63;
  const int lo = lane & 15, hi = lane >> 4;
  const int id = (blockIdx.x << 2) + wave;  // 0..16383
  const int win = id >> 3, h = id & 7;
  const bf16_t* qb = q + (size_t)win * (64 * 256) + h * 32;
  const bf16_t* kb = k + (size_t)win * (64 * 256) + h * 32;
  const bf16_t* vb = v + (size_t)win * (64 * 256) + h * 32;

  // QK^T (K-dim = 32 = one mfma step)
  bf16x8 qa[4], ka[4];
#pragma unroll
  for (int i = 0; i < 4; ++i)
    qa[i] = *reinterpret_cast<const bf16x8*>(qb + (size_t)((i << 4) + lo) * 256 + (hi << 3));
#pragma unroll
  for (int j = 0; j < 4; ++j)
    ka[j] = *reinterpret_cast<const bf16x8*>(kb + (size_t)((j << 4) + lo) * 256 + (hi << 3));
  f32x4 s[4][4] = {};
#pragma unroll
  for (int i = 0; i < 4; ++i)
#pragma unroll
    for (int j = 0; j < 4; ++j) s[i][j] = mfma16(qa[i], ka[j], s[i][j]);

  // stage V transposed into LDS: Vt[d][m], stride 72 (16B-aligned rows)
#pragma unroll
  for (int it = 0; it < 4; ++it) {
    int ch = (it << 6) + lane;
    int m = ch >> 2, d0 = (ch & 3) << 3;
    bf16x8 v8 = *reinterpret_cast<const bf16x8*>(vb + (size_t)m * 256 + d0);
#pragma unroll
    for (int e = 0; e < 8; ++e) Vt[wave][(d0 + e) * 72 + m] = v8[e];
  }

  // scale + rel-pos bias + shift mask + row softmax (rows live in 16-lane groups)
  const int wh = (win & 63) >> 3, ww = win & 7;
  const float scale = 0.17677669529663687f;  // 1/sqrt(32)
  float pinv[4][4];
#pragma unroll
  for (int i = 0; i < 4; ++i) {
#pragma unroll
    for (int r = 0; r < 4; ++r) {
      int n = (i << 4) + (hi << 2) + r;
      int yn = n >> 3, xn = n & 7;
      int cn = regid(wh * 8 + yn) * 3 + regid(ww * 8 + xn);
      float vals[4], mx = -1e30f;
#pragma unroll
      for (int j = 0; j < 4; ++j) {
        int m = (j << 4) + lo;
        int ym = m >> 3, xm = m & 7;
        int cm = regid(wh * 8 + ym) * 3 + regid(ww * 8 + xm);
        float val = s[i][j][r] * scale + rpbt[((yn - ym + 7) * 15 + (xn - xm + 7)) * 8 + h];
        if (cn != cm) val -= 100.0f;
        vals[j] = val;
        mx = fmaxf(mx, val);
      }
#pragma unroll
      for (int d = 1; d < 16; d <<= 1) mx = fmaxf(mx, __shfl_xor(mx, d));
      float sum = 0.0f;
#pragma unroll
      for (int j = 0; j < 4; ++j) {
        float p = __expf(vals[j] - mx);
        sum += p;
        Pl[wave][n * 72 + (j << 4) + lo] = to_bf16(p);
      }
#pragma unroll
      for (int d = 1; d < 16; d <<= 1) sum += __shfl_xor(sum, d);
      pinv[i][r] = 1.0f / sum;
    }
  }

  // PV: O[64,32] = P[64,64] @ V[64,32]
  f32x4 oa[4][2] = {};
#pragma unroll
  for (int kt = 0; kt < 2; ++kt) {
    bf16x8 pa[4], va[2];
#pragma unroll
    for (int i = 0; i < 4; ++i)
      pa[i] = *reinterpret_cast<const bf16x8*>(&Pl[wave][((i << 4) + lo) * 72 + (kt << 5) + (hi << 3)]);
#pragma unroll
    for (int dt = 0; dt < 2; ++dt)
      va[dt] = *reinterpret_cast<const bf16x8*>(&Vt[wave][((dt << 4) + lo) * 72 + (kt << 5) + (hi << 3)]);
#pragma unroll
    for (int i = 0; i < 4; ++i)
#pragma unroll
      for (int dt = 0; dt < 2; ++dt) oa[i][dt] = mfma16(pa[i], va[dt], oa[i][dt]);
  }

  bf16_t* ob = o + (size_t)win * (64 * 256) + h * 32;
#pragma unroll
  for (int i = 0; i < 4; ++i)
#pragma unroll
    for (int r = 0; r < 4; ++r) {
      int n = (i << 4) + (hi << 2) + r;
      float piv = pinv[i][r];
#pragma unroll
      for (int dt = 0; dt < 2; ++dt)
        ob[(size_t)n * 256 + (dt << 4) + lo] = to_bf16(oa[i][dt][r] * piv);
    }
}

// ---------------- launch ----------------
extern "C" void kernel_launch(void* const* d_in, const int* in_sizes, int n_in,
                              void* d_out, int out_size, void* d_ws, size_t ws_size,
                              hipStream_t stream) {
  const float* x      = (const float*)d_in[0];
  const float* n1g    = (const float*)d_in[1];
  const float* n1b    = (const float*)d_in[2];
  const float* qkv_w  = (const float*)d_in[3];
  const float* qkv_b  = (const float*)d_in[4];
  const float* rpbt   = (const float*)d_in[5];
  const float* proj_w = (const float*)d_in[6];
  const float* proj_b = (const float*)d_in[7];
  const float* n2g    = (const float*)d_in[8];
  const float* n2b    = (const float*)d_in[9];
  const float* fc1_w  = (const float*)d_in[10];
  const float* fc1_b  = (const float*)d_in[11];
  const float* fc2_w  = (const float*)d_in[12];
  const float* fc2_b  = (const float*)d_in[13];
  float* out = (float*)d_out;
  char*  ws  = (char*)d_ws;

  // ws layout (peak ~130 MB):
  //   [0,   64MB): hln  -> obuf -> h2 chunk (time-shared, strictly sequential lifetimes)
  //   [64, 128MB): qbuf -> x2n
  //   [128MB, +1.5MB): bf16 weights
  // d_out doubles as scratch: k,v bf16 until attention, then x2/out fp32.
  const size_t MB64 = 67108864;
  bf16_t* hln  = (bf16_t*)(ws);
  bf16_t* obuf = (bf16_t*)(ws);
  bf16_t* h2   = (bf16_t*)(ws);
  bf16_t* qbuf = (bf16_t*)(ws + MB64);
  bf16_t* x2n  = (bf16_t*)(ws + MB64);
  bf16_t* wb   = (bf16_t*)(ws + 2 * MB64);
  bf16_t* qkv_wb  = wb;                   // 196608
  bf16_t* proj_wb = qkv_wb + 196608;      // 65536
  bf16_t* fc1_wb  = proj_wb + 65536;      // 262144
  bf16_t* fc2_wb  = fc1_wb + 262144;      // 262144
  bf16_t* kbuf = (bf16_t*)d_out;          // 33554432 elements
  bf16_t* vbuf = kbuf + 33554432;

  cvt_kernel<<<768, 256, 0, stream>>>(qkv_w, qkv_wb, 196608);
  cvt_kernel<<<256, 256, 0, stream>>>(proj_w, proj_wb, 65536);
  cvt_kernel<<<1024, 256, 0, stream>>>(fc1_w, fc1_wb, 262144);
  cvt_kernel<<<1024, 256, 0, stream>>>(fc2_w, fc2_wb, 262144);

  // LN1 + shift + window partition
  ln_kernel<true><<<32768, 256, 0, stream>>>(x, n1g, n1b, hln);

  // QKV projections (B^T weights; q/k/v = row blocks of qkv_w)
  gemm_bt<0><<<dim3(1024, 2), 256, 0, stream>>>(hln, qkv_wb,              qkv_b,       qbuf, nullptr, MROWS, 256, 256);
  gemm_bt<0><<<dim3(1024, 2), 256, 0, stream>>>(hln, qkv_wb + 256 * 256,  qkv_b + 256, kbuf, nullptr, MROWS, 256, 256);
  gemm_bt<0><<<dim3(1024, 2), 256, 0, stream>>>(hln, qkv_wb + 512 * 256,  qkv_b + 512, vbuf, nullptr, MROWS, 256, 256);

  // windowed attention (16384 window-heads, 4 per block)
  attn_kernel<<<4096, 256, 0, stream>>>(qbuf, kbuf, vbuf, rpbt, obuf);

  // proj + window-reverse + unshift + residual -> x2 (fp32, into d_out)
  gemm_bt<2><<<dim3(1024, 2), 256, 0, stream>>>(obuf, proj_wb, proj_b, out, x, MROWS, 256, 256);

  // LN2
  ln_kernel<false><<<32768, 256, 0, stream>>>(out, n2g, n2b, x2n);

  // MLP in 4 row-chunks (h2 chunk = 32768 x 1024 bf16 = 64MB)
  for (int c = 0; c < 4; ++c) {
    const bf16_t* xa = x2n + (size_t)c * 32768 * 256;
    gemm_bt<1><<<dim3(256, 8), 256, 0, stream>>>(xa, fc1_wb, fc1_b, h2, nullptr, 32768, 1024, 256);
    gemm_bt<3><<<dim3(256, 2), 256, 0, stream>>>(h2, fc2_wb, fc2_b, out + (size_t)c * 32768 * 256,
                                                 nullptr, 32768, 256, 1024);
  }
}

// Round 2
// 681.365 us; speedup vs baseline: 1.0331x; 1.0331x over previous
//
#include <hip/hip_runtime.h>
#include <hip/hip_bf16.h>
#include <stdint.h>

typedef __bf16 bf16_t;
typedef __bf16 bf16x8 __attribute__((ext_vector_type(8)));
typedef __bf16 bf16x4 __attribute__((ext_vector_type(4)));
typedef float f32x4 __attribute__((ext_vector_type(4)));

// Problem constants: B=32, H=W=64, C=256, heads=8, ws=8, ss=4
#define MROWS 131072   // B * 64 * 64 tokens (window layout rows)

__device__ __forceinline__ bf16_t to_bf16(float f) {
  __hip_bfloat16 h = __float2bfloat16(f);   // RNE
  return *reinterpret_cast<bf16_t*>(&h);
}

__device__ __forceinline__ f32x4 mfma16(bf16x8 a, bf16x8 b, f32x4 c) {
  return __builtin_amdgcn_mfma_f32_16x16x32_bf16(a, b, c, 0, 0, 0);
}

__device__ __forceinline__ void gload16(const void* g, void* l) {
  __builtin_amdgcn_global_load_lds(
      (const __attribute__((address_space(1))) void*)g,
      (__attribute__((address_space(3))) void*)l, 16, 0, 0);
}

// window-layout row m  ->  x row (shift+partition gather for LN1; reverse+unshift
// scatter for the proj epilogue: same bijection)
__device__ __forceinline__ int map_row(int m) {
  int b   = m >> 12;
  int rem = m & 4095;
  int win = rem >> 6;
  int n   = rem & 63;
  int gh  = ((win >> 3) << 3) + (n >> 3);
  int gw  = ((win & 7) << 3) + (n & 7);
  int sh  = (gh + 4) & 63;
  int sw  = (gw + 4) & 63;
  return (b << 12) + (sh << 6) + sw;
}

// ---------------- fp32 -> bf16 weight convert ----------------
__global__ __launch_bounds__(256) void cvt_kernel(const float* __restrict__ in,
                                                  bf16_t* __restrict__ out, int n) {
  int i = blockIdx.x * 256 + threadIdx.x;
  if (i < n) out[i] = to_bf16(in[i]);
}

// ---------------- bias table: bias[cls][h][n][m] = rpb(n,m,h) + mask(cls,n,m) ----------------
// cls = (wh==7)*2 + (ww==7); 4*8*64*64 floats = 512 KB
__global__ __launch_bounds__(256) void bias_kernel(const float* __restrict__ rpbt,
                                                   float* __restrict__ bias) {
  int idx = blockIdx.x * 256 + threadIdx.x;   // 0 .. 131071
  int m = idx & 63, n = (idx >> 6) & 63, h = (idx >> 12) & 7, c = idx >> 15;
  int yn = n >> 3, xn = n & 7, ym = m >> 3, xm = m & 7;
  float v = rpbt[((yn - ym + 7) * 15 + (xn - xm + 7)) * 8 + h];
  int rn = (c & 2) ? (yn < 4 ? 1 : 2) : 0;
  int cn = (c & 1) ? (xn < 4 ? 1 : 2) : 0;
  int rm = (c & 2) ? (ym < 4 ? 1 : 2) : 0;
  int cm = (c & 1) ? (xm < 4 ? 1 : 2) : 0;
  if (rn * 3 + cn != rm * 3 + cm) v -= 100.0f;
  bias[idx] = v;
}

// ---------------- LayerNorm (wave per row), optional row-permuted gather ----------------
template <bool PERM>
__global__ __launch_bounds__(256) void ln_kernel(const float* __restrict__ xin,
                                                 const float* __restrict__ g,
                                                 const float* __restrict__ b,
                                                 bf16_t* __restrict__ out) {
  int row  = (blockIdx.x << 2) + (threadIdx.x >> 6);
  int lane = threadIdx.x & 63;
  int src  = PERM ? map_row(row) : row;
  float4 v = *reinterpret_cast<const float4*>(xin + (size_t)src * 256 + (lane << 2));
  float s = v.x + v.y + v.z + v.w;
#pragma unroll
  for (int d = 1; d < 64; d <<= 1) s += __shfl_xor(s, d);
  float mean = s * 0.00390625f;
  float ax = v.x - mean, ay = v.y - mean, az = v.z - mean, aw = v.w - mean;
  float s2 = ax * ax + ay * ay + az * az + aw * aw;
#pragma unroll
  for (int d = 1; d < 64; d <<= 1) s2 += __shfl_xor(s2, d);
  float rstd = rsqrtf(s2 * 0.00390625f + 1e-5f);
  float4 gv = *reinterpret_cast<const float4*>(g + (lane << 2));
  float4 bv = *reinterpret_cast<const float4*>(b + (lane << 2));
  bf16x4 o4;
  o4[0] = to_bf16(ax * rstd * gv.x + bv.x);
  o4[1] = to_bf16(ay * rstd * gv.y + bv.y);
  o4[2] = to_bf16(az * rstd * gv.z + bv.z);
  o4[3] = to_bf16(aw * rstd * gv.w + bv.w);
  *reinterpret_cast<bf16x4*>(out + (size_t)row * 256 + (lane << 2)) = o4;
}

// ---------------- bf16 GEMM, B^T weights (m97 structure): out[m,n] = sum_k A[m,k]*W[n,k] + bias[n]
// EPI 0: store bf16                    EPI 1: GELU(exact) then bf16
// EPI 2: fp32 permuted-row store + residual from resid[]
// EPI 3: fp32 in-place += (stride 256)
// EPI 4: qkv head-major split: col -> {q,k,v}[h][row][d], bf16
template <int EPI>
__global__ __launch_bounds__(256) void gemm_bt(const bf16_t* __restrict__ A,
                                               const bf16_t* __restrict__ W,
                                               const float* __restrict__ bias,
                                               void* __restrict__ outp,
                                               void* __restrict__ outp2,
                                               void* __restrict__ outp3,
                                               const float* __restrict__ resid,
                                               int M, int N, int K) {
  __shared__ __align__(16) bf16_t As[128 * 32];
  __shared__ __align__(16) bf16_t Bs[128 * 32];
  const int tid  = threadIdx.x;
  const int lane = tid & 63, lo = lane & 15, hi = lane >> 4;
  const int wave = tid >> 6;
  const int bm = blockIdx.x << 7, bn = blockIdx.y << 7;
  const int wr = (wave >> 1) << 6, wc = (wave & 1) << 6;
  f32x4 acc[4][4] = {};

  for (int k0 = 0; k0 < K; k0 += 32) {
    __syncthreads();
#pragma unroll
    for (int it = 0; it < 2; ++it) {
      int ch = (it << 8) + tid;           // 512 chunks of 16B per tile
      int r = ch >> 2, kf = (ch & 3) << 3;
      gload16(A + (size_t)(bm + r) * K + (k0 + kf), &As[ch << 3]);
      gload16(W + (size_t)(bn + r) * K + (k0 + kf), &Bs[ch << 3]);
    }
    __syncthreads();
    bf16x8 af[4], bfr[4];
#pragma unroll
    for (int i = 0; i < 4; ++i)
      af[i] = *reinterpret_cast<const bf16x8*>(&As[(wr + (i << 4) + lo) * 32 + (hi << 3)]);
#pragma unroll
    for (int j = 0; j < 4; ++j)
      bfr[j] = *reinterpret_cast<const bf16x8*>(&Bs[(wc + (j << 4) + lo) * 32 + (hi << 3)]);
#pragma unroll
    for (int i = 0; i < 4; ++i)
#pragma unroll
      for (int j = 0; j < 4; ++j)
        acc[i][j] = mfma16(af[i], bfr[j], acc[i][j]);
  }

  float bv[4];
#pragma unroll
  for (int j = 0; j < 4; ++j) bv[j] = bias[bn + wc + (j << 4) + lo];

#pragma unroll
  for (int i = 0; i < 4; ++i) {
#pragma unroll
    for (int r = 0; r < 4; ++r) {
      int row = bm + wr + (i << 4) + (hi << 2) + r;
      if constexpr (EPI == 2) {
        int xr = map_row(row);
        float* o = (float*)outp;
#pragma unroll
        for (int j = 0; j < 4; ++j) {
          int col = bn + wc + (j << 4) + lo;
          size_t idx = (size_t)xr * 256 + col;
          o[idx] = resid[idx] + acc[i][j][r] + bv[j];
        }
      } else if constexpr (EPI == 3) {
        float* o = (float*)outp;
#pragma unroll
        for (int j = 0; j < 4; ++j) {
          int col = bn + wc + (j << 4) + lo;
          size_t idx = (size_t)row * 256 + col;
          o[idx] = o[idx] + acc[i][j][r] + bv[j];
        }
      } else if constexpr (EPI == 4) {
#pragma unroll
        for (int j = 0; j < 4; ++j) {
          int col = bn + wc + (j << 4) + lo;   // 0..767
          bf16_t* base = (col < 256) ? (bf16_t*)outp
                        : (col < 512) ? (bf16_t*)outp2 : (bf16_t*)outp3;
          int hd = (col >> 5) & 7, d = col & 31;
          base[((size_t)hd * MROWS + row) * 32 + d] = to_bf16(acc[i][j][r] + bv[j]);
        }
      } else {
        bf16_t* o = (bf16_t*)outp;
#pragma unroll
        for (int j = 0; j < 4; ++j) {
          int col = bn + wc + (j << 4) + lo;
          float v = acc[i][j][r] + bv[j];
          if constexpr (EPI == 1) v = 0.5f * v * (1.0f + erff(v * 0.70710678118654752f));
          o[(size_t)row * N + col] = to_bf16(v);
        }
      }
    }
  }
}

// ---------------- windowed attention: one wave per (window, head) ----------------
// qh,kh,vh: head-major [8][131072][32] bf16; o: token-major [131072][256] bf16
__global__ __launch_bounds__(256) void attn_kernel(const bf16_t* __restrict__ qh,
                                                   const bf16_t* __restrict__ kh,
                                                   const bf16_t* __restrict__ vh,
                                                   const float* __restrict__ bias,
                                                   bf16_t* __restrict__ o) {
  __shared__ __align__(16) bf16_t Pl[4][64 * 72];
  __shared__ __align__(16) bf16_t Vt[4][32 * 72];
  const int wave = threadIdx.x >> 6, lane = threadIdx.x & 63;
  const int lo = lane & 15, hi = lane >> 4;
  const int id = (blockIdx.x << 2) + wave;  // 0..16383
  const int win = id >> 3, h = id & 7;
  const size_t hb = ((size_t)h * MROWS + (size_t)win * 64) * 32;
  const bf16_t* qb = qh + hb;
  const bf16_t* kb = kh + hb;
  const bf16_t* vb = vh + hb;

  // stage V transposed into LDS: Vt[d][m], stride 72 (coalesced 16B reads)
  const bf16_t* vbl = vb + lane * 32;
#pragma unroll
  for (int c4 = 0; c4 < 4; ++c4) {
    bf16x8 v8 = *reinterpret_cast<const bf16x8*>(vbl + (c4 << 3));
#pragma unroll
    for (int e = 0; e < 8; ++e) Vt[wave][((c4 << 3) + e) * 72 + lane] = v8[e];
  }

  // QK^T (K-dim = 32 = one mfma step); fully-coalesced fragment loads
  bf16x8 qa[4], ka[4];
#pragma unroll
  for (int i = 0; i < 4; ++i)
    qa[i] = *reinterpret_cast<const bf16x8*>(qb + ((i << 4) + lo) * 32 + (hi << 3));
#pragma unroll
  for (int j = 0; j < 4; ++j)
    ka[j] = *reinterpret_cast<const bf16x8*>(kb + ((j << 4) + lo) * 32 + (hi << 3));
  f32x4 s[4][4] = {};
#pragma unroll
  for (int i = 0; i < 4; ++i)
#pragma unroll
    for (int j = 0; j < 4; ++j) s[i][j] = mfma16(qa[i], ka[j], s[i][j]);

  // precomputed rpb+mask table for this (class, head)
  const int wh = (win & 63) >> 3, ww = win & 7;
  const int cls = ((wh == 7) ? 2 : 0) + ((ww == 7) ? 1 : 0);
  const float* bb = bias + ((size_t)cls * 8 + h) * 4096;
  const float scale = 0.17677669529663687f;  // 1/sqrt(32)

  float pinv[4][4];
#pragma unroll
  for (int i = 0; i < 4; ++i) {
#pragma unroll
    for (int r = 0; r < 4; ++r) {
      int n = (i << 4) + (hi << 2) + r;
      const float* brow = bb + n * 64 + lo;
      float vals[4], mx = -1e30f;
#pragma unroll
      for (int j = 0; j < 4; ++j) {
        float val = s[i][j][r] * scale + brow[j << 4];
        vals[j] = val;
        mx = fmaxf(mx, val);
      }
#pragma unroll
      for (int d = 1; d < 16; d <<= 1) mx = fmaxf(mx, __shfl_xor(mx, d));
      float sum = 0.0f;
#pragma unroll
      for (int j = 0; j < 4; ++j) {
        float p = __expf(vals[j] - mx);
        sum += p;
        Pl[wave][n * 72 + (j << 4) + lo] = to_bf16(p);
      }
#pragma unroll
      for (int d = 1; d < 16; d <<= 1) sum += __shfl_xor(sum, d);
      pinv[i][r] = 1.0f / sum;
    }
  }

  __syncthreads();   // Vt + Pl cross-lane LDS visibility

  // PV: O[64,32] = P[64,64] @ V[64,32]
  f32x4 oa[4][2] = {};
#pragma unroll
  for (int kt = 0; kt < 2; ++kt) {
    bf16x8 pa[4], va[2];
#pragma unroll
    for (int i = 0; i < 4; ++i)
      pa[i] = *reinterpret_cast<const bf16x8*>(&Pl[wave][((i << 4) + lo) * 72 + (kt << 5) + (hi << 3)]);
#pragma unroll
    for (int dt = 0; dt < 2; ++dt)
      va[dt] = *reinterpret_cast<const bf16x8*>(&Vt[wave][((dt << 4) + lo) * 72 + (kt << 5) + (hi << 3)]);
#pragma unroll
    for (int i = 0; i < 4; ++i)
#pragma unroll
      for (int dt = 0; dt < 2; ++dt) oa[i][dt] = mfma16(pa[i], va[dt], oa[i][dt]);
  }

  bf16_t* ob = o + (size_t)win * (64 * 256) + h * 32;
#pragma unroll
  for (int i = 0; i < 4; ++i)
#pragma unroll
    for (int r = 0; r < 4; ++r) {
      int n = (i << 4) + (hi << 2) + r;
      float piv = pinv[i][r];
#pragma unroll
      for (int dt = 0; dt < 2; ++dt)
        ob[(size_t)n * 256 + (dt << 4) + lo] = to_bf16(oa[i][dt][r] * piv);
    }
}

// ---------------- launch ----------------
extern "C" void kernel_launch(void* const* d_in, const int* in_sizes, int n_in,
                              void* d_out, int out_size, void* d_ws, size_t ws_size,
                              hipStream_t stream) {
  const float* x      = (const float*)d_in[0];
  const float* n1g    = (const float*)d_in[1];
  const float* n1b    = (const float*)d_in[2];
  const float* qkv_w  = (const float*)d_in[3];
  const float* qkv_b  = (const float*)d_in[4];
  const float* rpbt   = (const float*)d_in[5];
  const float* proj_w = (const float*)d_in[6];
  const float* proj_b = (const float*)d_in[7];
  const float* n2g    = (const float*)d_in[8];
  const float* n2b    = (const float*)d_in[9];
  const float* fc1_w  = (const float*)d_in[10];
  const float* fc1_b  = (const float*)d_in[11];
  const float* fc2_w  = (const float*)d_in[12];
  const float* fc2_b  = (const float*)d_in[13];
  float* out = (float*)d_out;
  char*  ws  = (char*)d_ws;

  // ws layout (peak ~130 MB):
  //   [0,   64MB): hln  -> obuf -> h2 chunk   (sequential lifetimes)
  //   [64, 128MB): qbuf -> x2n
  //   [128MB, +1.5MB): bf16 weights ; then 512KB bias table
  // d_out doubles as scratch: k,v bf16 (head-major) until attention, then x2/out fp32.
  const size_t MB64 = 67108864;
  bf16_t* hln  = (bf16_t*)(ws);
  bf16_t* obuf = (bf16_t*)(ws);
  bf16_t* h2   = (bf16_t*)(ws);
  bf16_t* qbuf = (bf16_t*)(ws + MB64);
  bf16_t* x2n  = (bf16_t*)(ws + MB64);
  bf16_t* wb   = (bf16_t*)(ws + 2 * MB64);
  bf16_t* qkv_wb  = wb;                   // 196608 el
  bf16_t* proj_wb = qkv_wb + 196608;      // 65536
  bf16_t* fc1_wb  = proj_wb + 65536;      // 262144
  bf16_t* fc2_wb  = fc1_wb + 262144;      // 262144
  float*  biast   = (float*)(fc2_wb + 262144);  // 131072 floats = 512KB
  bf16_t* kbuf = (bf16_t*)d_out;          // 33554432 el (64MB)
  bf16_t* vbuf = kbuf + 33554432;

  cvt_kernel<<<768, 256, 0, stream>>>(qkv_w, qkv_wb, 196608);
  cvt_kernel<<<256, 256, 0, stream>>>(proj_w, proj_wb, 65536);
  cvt_kernel<<<1024, 256, 0, stream>>>(fc1_w, fc1_wb, 262144);
  cvt_kernel<<<1024, 256, 0, stream>>>(fc2_w, fc2_wb, 262144);
  bias_kernel<<<512, 256, 0, stream>>>(rpbt, biast);

  // LN1 + shift + window partition
  ln_kernel<true><<<32768, 256, 0, stream>>>(x, n1g, n1b, hln);

  // fused QKV projection -> head-major q/k/v
  gemm_bt<4><<<dim3(1024, 6), 256, 0, stream>>>(hln, qkv_wb, qkv_b, qbuf, kbuf, vbuf,
                                                nullptr, MROWS, 768, 256);

  // windowed attention (16384 window-heads, 4 per block)
  attn_kernel<<<4096, 256, 0, stream>>>(qbuf, kbuf, vbuf, biast, obuf);

  // proj + window-reverse + unshift + residual -> x2 (fp32, into d_out)
  gemm_bt<2><<<dim3(1024, 2), 256, 0, stream>>>(obuf, proj_wb, proj_b, out, nullptr, nullptr,
                                                x, MROWS, 256, 256);

  // LN2
  ln_kernel<false><<<32768, 256, 0, stream>>>(out, n2g, n2b, x2n);

  // MLP in 4 row-chunks (h2 chunk = 32768 x 1024 bf16 = 64MB)
  for (int c = 0; c < 4; ++c) {
    const bf16_t* xa = x2n + (size_t)c * 32768 * 256;
    gemm_bt<1><<<dim3(256, 8), 256, 0, stream>>>(xa, fc1_wb, fc1_b, h2, nullptr, nullptr,
                                                 nullptr, 32768, 1024, 256);
    gemm_bt<3><<<dim3(256, 2), 256, 0, stream>>>(h2, fc2_wb, fc2_b, out + (size_t)c * 32768 * 256,
                                                 nullptr, nullptr, nullptr, 32768, 256, 1024);
  }
}

// Round 3
// 644.428 us; speedup vs baseline: 1.0923x; 1.0573x over previous
//
#include <hip/hip_runtime.h>
#include <hip/hip_bf16.h>
#include <stdint.h>

typedef __bf16 bf16_t;
typedef __bf16 bf16x8 __attribute__((ext_vector_type(8)));
typedef float f32x4 __attribute__((ext_vector_type(4)));

// Problem constants: B=32, H=W=64, C=256, heads=8, ws=8, ss=4
#define MROWS 131072   // B * 64 * 64 tokens

__device__ __forceinline__ bf16_t to_bf16(float f) {
  __hip_bfloat16 h = __float2bfloat16(f);   // RNE
  return *reinterpret_cast<bf16_t*>(&h);
}

__device__ __forceinline__ f32x4 mfma16(bf16x8 a, bf16x8 b, f32x4 c) {
  return __builtin_amdgcn_mfma_f32_16x16x32_bf16(a, b, c, 0, 0, 0);
}

__device__ __forceinline__ void gload16(const void* g, void* l) {
  __builtin_amdgcn_global_load_lds(
      (const __attribute__((address_space(1))) void*)g,
      (__attribute__((address_space(3))) void*)l, 16, 0, 0);
}

// window-layout row m  ->  x row (shift+partition gather; reverse+unshift scatter)
__device__ __forceinline__ int map_row(int m) {
  int b   = m >> 12;
  int rem = m & 4095;
  int win = rem >> 6;
  int n   = rem & 63;
  int gh  = ((win >> 3) << 3) + (n >> 3);
  int gw  = ((win & 7) << 3) + (n & 7);
  int sh  = (gh + 4) & 63;
  int sw  = (gw + 4) & 63;
  return (b << 12) + (sh << 6) + sw;
}

// ---------------- fp32 -> bf16 weight convert ----------------
__global__ __launch_bounds__(256) void cvt_kernel(const float* __restrict__ in,
                                                  bf16_t* __restrict__ out, int n) {
  int i = blockIdx.x * 256 + threadIdx.x;
  if (i < n) out[i] = to_bf16(in[i]);
}

// ---------------- bias table: bias[cls][h][n][m] = rpb(n,m,h) + mask(cls,n,m) ----------------
__global__ __launch_bounds__(256) void bias_kernel(const float* __restrict__ rpbt,
                                                   float* __restrict__ bias) {
  int idx = blockIdx.x * 256 + threadIdx.x;   // 0 .. 131071
  int m = idx & 63, n = (idx >> 6) & 63, h = (idx >> 12) & 7, c = idx >> 15;
  int yn = n >> 3, xn = n & 7, ym = m >> 3, xm = m & 7;
  float v = rpbt[((yn - ym + 7) * 15 + (xn - xm + 7)) * 8 + h];
  int rn = (c & 2) ? (yn < 4 ? 1 : 2) : 0;
  int cn = (c & 1) ? (xn < 4 ? 1 : 2) : 0;
  int rm = (c & 2) ? (ym < 4 ? 1 : 2) : 0;
  int cm = (c & 1) ? (xm < 4 ? 1 : 2) : 0;
  if (rn * 3 + cn != rm * 3 + cm) v -= 100.0f;
  bias[idx] = v;
}

// ---------------- LayerNorm (wave per row) fp32 -> bf16 ----------------
__global__ __launch_bounds__(256) void ln_kernel(const float* __restrict__ xin,
                                                 const float* __restrict__ g,
                                                 const float* __restrict__ b,
                                                 bf16_t* __restrict__ out) {
  int row  = (blockIdx.x << 2) + (threadIdx.x >> 6);
  int lane = threadIdx.x & 63;
  float4 v = *reinterpret_cast<const float4*>(xin + (size_t)row * 256 + (lane << 2));
  float s = v.x + v.y + v.z + v.w;
#pragma unroll
  for (int d = 1; d < 64; d <<= 1) s += __shfl_xor(s, d);
  float mean = s * 0.00390625f;
  float ax = v.x - mean, ay = v.y - mean, az = v.z - mean, aw = v.w - mean;
  float s2 = ax * ax + ay * ay + az * az + aw * aw;
#pragma unroll
  for (int d = 1; d < 64; d <<= 1) s2 += __shfl_xor(s2, d);
  float rstd = rsqrtf(s2 * 0.00390625f + 1e-5f);
  float4 gv = *reinterpret_cast<const float4*>(g + (lane << 2));
  float4 bv = *reinterpret_cast<const float4*>(b + (lane << 2));
  typedef __bf16 bf16x4 __attribute__((ext_vector_type(4)));
  bf16x4 o4;
  o4[0] = to_bf16(ax * rstd * gv.x + bv.x);
  o4[1] = to_bf16(ay * rstd * gv.y + bv.y);
  o4[2] = to_bf16(az * rstd * gv.z + bv.z);
  o4[3] = to_bf16(aw * rstd * gv.w + bv.w);
  *reinterpret_cast<bf16x4*>(out + (size_t)row * 256 + (lane << 2)) = o4;
}

// ---------------- bf16 GEMM, B^T weights (m97 structure), grid: x=bn (fast), y=bm
// EPI 1: GELU(exact) then bf16     EPI 3: fp32 in-place += (stride 256)
template <int EPI>
__global__ __launch_bounds__(256) void gemm_bt(const bf16_t* __restrict__ A,
                                               const bf16_t* __restrict__ W,
                                               const float* __restrict__ bias,
                                               void* __restrict__ outp,
                                               int M, int N, int K) {
  __shared__ __align__(16) bf16_t As[128 * 32];
  __shared__ __align__(16) bf16_t Bs[128 * 32];
  const int tid  = threadIdx.x;
  const int lane = tid & 63, lo = lane & 15, hi = lane >> 4;
  const int wave = tid >> 6;
  const int bm = blockIdx.y << 7, bn = blockIdx.x << 7;   // bn fastest -> A-tile L3-hot
  const int wr = (wave >> 1) << 6, wc = (wave & 1) << 6;
  f32x4 acc[4][4] = {};

  for (int k0 = 0; k0 < K; k0 += 32) {
    __syncthreads();
#pragma unroll
    for (int it = 0; it < 2; ++it) {
      int ch = (it << 8) + tid;
      int r = ch >> 2, kf = (ch & 3) << 3;
      gload16(A + (size_t)(bm + r) * K + (k0 + kf), &As[ch << 3]);
      gload16(W + (size_t)(bn + r) * K + (k0 + kf), &Bs[ch << 3]);
    }
    __syncthreads();
    bf16x8 af[4], bfr[4];
#pragma unroll
    for (int i = 0; i < 4; ++i)
      af[i] = *reinterpret_cast<const bf16x8*>(&As[(wr + (i << 4) + lo) * 32 + (hi << 3)]);
#pragma unroll
    for (int j = 0; j < 4; ++j)
      bfr[j] = *reinterpret_cast<const bf16x8*>(&Bs[(wc + (j << 4) + lo) * 32 + (hi << 3)]);
#pragma unroll
    for (int i = 0; i < 4; ++i)
#pragma unroll
      for (int j = 0; j < 4; ++j)
        acc[i][j] = mfma16(af[i], bfr[j], acc[i][j]);
  }

  float bv[4];
#pragma unroll
  for (int j = 0; j < 4; ++j) bv[j] = bias[bn + wc + (j << 4) + lo];

#pragma unroll
  for (int i = 0; i < 4; ++i) {
#pragma unroll
    for (int r = 0; r < 4; ++r) {
      int row = bm + wr + (i << 4) + (hi << 2) + r;
      if constexpr (EPI == 3) {
        float* o = (float*)outp;
#pragma unroll
        for (int j = 0; j < 4; ++j) {
          int col = bn + wc + (j << 4) + lo;
          size_t idx = (size_t)row * 256 + col;
          o[idx] = o[idx] + acc[i][j][r] + bv[j];
        }
      } else {
        bf16_t* o = (bf16_t*)outp;
#pragma unroll
        for (int j = 0; j < 4; ++j) {
          int col = bn + wc + (j << 4) + lo;
          float v = acc[i][j][r] + bv[j];
          if constexpr (EPI == 1) v = 0.5f * v * (1.0f + erff(v * 0.70710678118654752f));
          o[(size_t)row * N + col] = to_bf16(v);
        }
      }
    }
  }
}

// ---------------- mega: LN1+shift+QKV+attention+proj+residual, one block per window ----
// 8 waves = 8 heads, 512 threads. Dynamic LDS 152576 B:
//   A_lds [64][264] bf16 (33792 B)  -- LN'd activations; later overlaid by O [64][264]
//   per-wave (7424 el): q[64][40] | k[64][40] | Vt[32][72];  P[64][72] overlays q+k
__global__ __launch_bounds__(512, 2) void mega_attn(
    const float* __restrict__ x, const float* __restrict__ n1g,
    const float* __restrict__ n1b, const bf16_t* __restrict__ qkv_wb,
    const float* __restrict__ qkv_b, const bf16_t* __restrict__ proj_wb,
    const float* __restrict__ proj_b, const float* __restrict__ bias,
    float* __restrict__ out) {
  extern __shared__ __align__(16) char smem_raw[];
  bf16_t* Sm = (bf16_t*)smem_raw;
  bf16_t* A_lds = Sm;                       // [64][264] el (O_lds later)
  const int tid = threadIdx.x;
  const int lane = tid & 63, lo = lane & 15, hi = lane >> 4;
  const int h = tid >> 6;                   // wave id = head
  const int win = blockIdx.x;               // 0..2047
  bf16_t* Wv    = Sm + 16896 + h * 7424;
  bf16_t* q_lds = Wv;                       // [64][40]
  bf16_t* k_lds = Wv + 2560;                // [64][40]
  bf16_t* Vt    = Wv + 5120;                // [32][72]
  bf16_t* Pl    = Wv;                       // [64][72] overlays q+k (frag reads precede)

  // ---- P0: LN1 + shifted-window gather -> A_lds ----
  {
    const int row = tid >> 3, s = tid & 7;
    const int src = map_row((win << 6) + row);
    const float* xp = x + (size_t)src * 256 + (s << 5);
    float f[32];
#pragma unroll
    for (int c = 0; c < 8; ++c) {
      float4 v = *reinterpret_cast<const float4*>(xp + (c << 2));
      f[c * 4 + 0] = v.x; f[c * 4 + 1] = v.y; f[c * 4 + 2] = v.z; f[c * 4 + 3] = v.w;
    }
    float sum = 0.0f;
#pragma unroll
    for (int e = 0; e < 32; ++e) sum += f[e];
#pragma unroll
    for (int d = 1; d < 8; d <<= 1) sum += __shfl_xor(sum, d);
    float mean = sum * 0.00390625f;
    float var = 0.0f;
#pragma unroll
    for (int e = 0; e < 32; ++e) { float t = f[e] - mean; var += t * t; }
#pragma unroll
    for (int d = 1; d < 8; d <<= 1) var += __shfl_xor(var, d);
    float rstd = rsqrtf(var * 0.00390625f + 1e-5f);
    const float* gp = n1g + (s << 5);
    const float* bp = n1b + (s << 5);
#pragma unroll
    for (int c = 0; c < 4; ++c) {
      bf16x8 w;
#pragma unroll
      for (int e = 0; e < 8; ++e) {
        int idx = (c << 3) + e;
        w[e] = to_bf16((f[idx] - mean) * rstd * gp[idx] + bp[idx]);
      }
      *reinterpret_cast<bf16x8*>(&A_lds[row * 264 + (s << 5) + (c << 3)]) = w;
    }
  }
  __syncthreads();

  // ---- P1: per-head QKV, transposed accs: acc[i][j] holds X[n=j*16+lo][d=i*16+hi*4+r] ----
  f32x4 aq[2][4] = {}, ak[2][4] = {}, av[2][4] = {};
#pragma unroll 2
  for (int kk = 0; kk < 8; ++kk) {
    const int k0 = kk << 5;
    bf16x8 fb[4];
#pragma unroll
    for (int j = 0; j < 4; ++j)
      fb[j] = *reinterpret_cast<const bf16x8*>(&A_lds[((j << 4) + lo) * 264 + k0 + (hi << 3)]);
    bf16x8 wfq[2], wfk[2], wfv[2];
#pragma unroll
    for (int i = 0; i < 2; ++i) {
      int drow = h * 32 + (i << 4) + lo;
      wfq[i] = *reinterpret_cast<const bf16x8*>(qkv_wb + (size_t)(drow      ) * 256 + k0 + (hi << 3));
      wfk[i] = *reinterpret_cast<const bf16x8*>(qkv_wb + (size_t)(drow + 256) * 256 + k0 + (hi << 3));
      wfv[i] = *reinterpret_cast<const bf16x8*>(qkv_wb + (size_t)(drow + 512) * 256 + k0 + (hi << 3));
    }
#pragma unroll
    for (int i = 0; i < 2; ++i)
#pragma unroll
      for (int j = 0; j < 4; ++j) {
        aq[i][j] = mfma16(wfq[i], fb[j], aq[i][j]);
        ak[i][j] = mfma16(wfk[i], fb[j], ak[i][j]);
        av[i][j] = mfma16(wfv[i], fb[j], av[i][j]);
      }
  }

  // ---- P2: dump q,k,Vt into per-wave LDS (+bias) ----
#pragma unroll
  for (int i = 0; i < 2; ++i)
#pragma unroll
    for (int r = 0; r < 4; ++r) {
      int d = (i << 4) + (hi << 2) + r;
      float bq = qkv_b[h * 32 + d];
      float bk = qkv_b[256 + h * 32 + d];
      float bv = qkv_b[512 + h * 32 + d];
#pragma unroll
      for (int j = 0; j < 4; ++j) {
        int n = (j << 4) + lo;
        q_lds[n * 40 + d] = to_bf16(aq[i][j][r] + bq);
        k_lds[n * 40 + d] = to_bf16(ak[i][j][r] + bk);
        Vt[d * 72 + n]    = to_bf16(av[i][j][r] + bv);
      }
    }

  // ---- P3: attention (per-wave; no cross-wave deps) ----
  bf16x8 qa[4], ka[4];
#pragma unroll
  for (int i = 0; i < 4; ++i)
    qa[i] = *reinterpret_cast<const bf16x8*>(&q_lds[((i << 4) + lo) * 40 + (hi << 3)]);
#pragma unroll
  for (int j = 0; j < 4; ++j)
    ka[j] = *reinterpret_cast<const bf16x8*>(&k_lds[((j << 4) + lo) * 40 + (hi << 3)]);
  f32x4 s4[4][4] = {};
#pragma unroll
  for (int i = 0; i < 4; ++i)
#pragma unroll
    for (int j = 0; j < 4; ++j) s4[i][j] = mfma16(qa[i], ka[j], s4[i][j]);

  const int wh = (win & 63) >> 3, ww = win & 7;
  const int cls = ((wh == 7) ? 2 : 0) + ((ww == 7) ? 1 : 0);
  const float* bb = bias + ((size_t)cls * 8 + h) * 4096;
  const float scale = 0.17677669529663687f;  // 1/sqrt(32)

  float pinv[4][4];
#pragma unroll
  for (int i = 0; i < 4; ++i) {
#pragma unroll
    for (int r = 0; r < 4; ++r) {
      int n = (i << 4) + (hi << 2) + r;
      const float* brow = bb + n * 64 + lo;
      float vals[4], mx = -1e30f;
#pragma unroll
      for (int j = 0; j < 4; ++j) {
        float val = s4[i][j][r] * scale + brow[j << 4];
        vals[j] = val;
        mx = fmaxf(mx, val);
      }
#pragma unroll
      for (int d = 1; d < 16; d <<= 1) mx = fmaxf(mx, __shfl_xor(mx, d));
      float sum = 0.0f;
#pragma unroll
      for (int j = 0; j < 4; ++j) {
        float p = __expf(vals[j] - mx);
        sum += p;
        Pl[n * 72 + (j << 4) + lo] = to_bf16(p);
      }
#pragma unroll
      for (int d = 1; d < 16; d <<= 1) sum += __shfl_xor(sum, d);
      pinv[i][r] = 1.0f / sum;
    }
  }

  // PV: O[64,32] = P[64,64] @ V[64,32]
  f32x4 oa[4][2] = {};
#pragma unroll
  for (int kt = 0; kt < 2; ++kt) {
    bf16x8 pa[4], va[2];
#pragma unroll
    for (int i = 0; i < 4; ++i)
      pa[i] = *reinterpret_cast<const bf16x8*>(&Pl[((i << 4) + lo) * 72 + (kt << 5) + (hi << 3)]);
#pragma unroll
    for (int dt = 0; dt < 2; ++dt)
      va[dt] = *reinterpret_cast<const bf16x8*>(&Vt[((dt << 4) + lo) * 72 + (kt << 5) + (hi << 3)]);
#pragma unroll
    for (int i = 0; i < 4; ++i)
#pragma unroll
      for (int dt = 0; dt < 2; ++dt) oa[i][dt] = mfma16(pa[i], va[dt], oa[i][dt]);
  }

  // ---- P4: O -> O_lds (overlays A_lds; barrier: all waves done reading A) ----
  __syncthreads();
#pragma unroll
  for (int i = 0; i < 4; ++i)
#pragma unroll
    for (int r = 0; r < 4; ++r) {
      int n = (i << 4) + (hi << 2) + r;
      float piv = pinv[i][r];
#pragma unroll
      for (int dt = 0; dt < 2; ++dt)
        A_lds[n * 264 + h * 32 + (dt << 4) + lo] = to_bf16(oa[i][dt][r] * piv);
    }
  __syncthreads();

  // ---- P5: proj (wave owns 32 out-cols) + reverse-scatter + residual -> fp32 out ----
  f32x4 ap[4][2] = {};
#pragma unroll 2
  for (int kk = 0; kk < 8; ++kk) {
    const int k0 = kk << 5;
    bf16x8 fa[4], wp[2];
#pragma unroll
    for (int i = 0; i < 4; ++i)
      fa[i] = *reinterpret_cast<const bf16x8*>(&A_lds[((i << 4) + lo) * 264 + k0 + (hi << 3)]);
#pragma unroll
    for (int jj = 0; jj < 2; ++jj)
      wp[jj] = *reinterpret_cast<const bf16x8*>(proj_wb + (size_t)(h * 32 + (jj << 4) + lo) * 256 + k0 + (hi << 3));
#pragma unroll
    for (int i = 0; i < 4; ++i)
#pragma unroll
      for (int jj = 0; jj < 2; ++jj)
        ap[i][jj] = mfma16(fa[i], wp[jj], ap[i][jj]);
  }
#pragma unroll
  for (int i = 0; i < 4; ++i)
#pragma unroll
    for (int r = 0; r < 4; ++r) {
      int m = (i << 4) + (hi << 2) + r;
      int xr = map_row((win << 6) + m);
#pragma unroll
      for (int jj = 0; jj < 2; ++jj) {
        int col = h * 32 + (jj << 4) + lo;
        size_t idx = (size_t)xr * 256 + col;
        out[idx] = x[idx] + ap[i][jj][r] + proj_b[col];
      }
    }
}

// ---------------- launch ----------------
extern "C" void kernel_launch(void* const* d_in, const int* in_sizes, int n_in,
                              void* d_out, int out_size, void* d_ws, size_t ws_size,
                              hipStream_t stream) {
  const float* x      = (const float*)d_in[0];
  const float* n1g    = (const float*)d_in[1];
  const float* n1b    = (const float*)d_in[2];
  const float* qkv_w  = (const float*)d_in[3];
  const float* qkv_b  = (const float*)d_in[4];
  const float* rpbt   = (const float*)d_in[5];
  const float* proj_w = (const float*)d_in[6];
  const float* proj_b = (const float*)d_in[7];
  const float* n2g    = (const float*)d_in[8];
  const float* n2b    = (const float*)d_in[9];
  const float* fc1_w  = (const float*)d_in[10];
  const float* fc1_b  = (const float*)d_in[11];
  const float* fc2_w  = (const float*)d_in[12];
  const float* fc2_b  = (const float*)d_in[13];
  float* out = (float*)d_out;
  char*  ws  = (char*)d_ws;

  // ws: [0,64MB) h2 chunk | [64,128MB) x2n | [128MB..] bf16 weights + bias table
  const size_t MB64 = 67108864;
  bf16_t* h2   = (bf16_t*)(ws);
  bf16_t* x2n  = (bf16_t*)(ws + MB64);
  bf16_t* wb   = (bf16_t*)(ws + 2 * MB64);
  bf16_t* qkv_wb  = wb;                   // 196608 el
  bf16_t* proj_wb = qkv_wb + 196608;      // 65536
  bf16_t* fc1_wb  = proj_wb + 65536;      // 262144
  bf16_t* fc2_wb  = fc1_wb + 262144;      // 262144
  float*  biast   = (float*)(fc2_wb + 262144);  // 131072 f32 = 512KB

  static const int MEGA_LDS = 152576;
  hipFuncSetAttribute(reinterpret_cast<const void*>(mega_attn),
                      hipFuncAttributeMaxDynamicSharedMemorySize, MEGA_LDS);

  cvt_kernel<<<768, 256, 0, stream>>>(qkv_w, qkv_wb, 196608);
  cvt_kernel<<<256, 256, 0, stream>>>(proj_w, proj_wb, 65536);
  cvt_kernel<<<1024, 256, 0, stream>>>(fc1_w, fc1_wb, 262144);
  cvt_kernel<<<1024, 256, 0, stream>>>(fc2_w, fc2_wb, 262144);
  bias_kernel<<<512, 256, 0, stream>>>(rpbt, biast);

  // LN1 + shift + QKV + attention + proj + residual -> x2 fp32 in d_out
  mega_attn<<<2048, 512, MEGA_LDS, stream>>>(x, n1g, n1b, qkv_wb, qkv_b,
                                             proj_wb, proj_b, biast, out);

  // LN2
  ln_kernel<<<32768, 256, 0, stream>>>(out, n2g, n2b, x2n);

  // MLP in 4 row-chunks (h2 chunk = 32768 x 1024 bf16 = 64MB)
  for (int c = 0; c < 4; ++c) {
    const bf16_t* xa = x2n + (size_t)c * 32768 * 256;
    gemm_bt<1><<<dim3(8, 256), 256, 0, stream>>>(xa, fc1_wb, fc1_b, h2, 32768, 1024, 256);
    gemm_bt<3><<<dim3(2, 256), 256, 0, stream>>>(h2, fc2_wb, fc2_b, out + (size_t)c * 32768 * 256,
                                                 32768, 256, 1024);
  }
}

// Round 4
// 617.627 us; speedup vs baseline: 1.1397x; 1.0434x over previous
//
#include <hip/hip_runtime.h>
#include <hip/hip_bf16.h>
#include <stdint.h>

typedef __bf16 bf16_t;
typedef __bf16 bf16x8 __attribute__((ext_vector_type(8)));
typedef float f32x4 __attribute__((ext_vector_type(4)));

// Problem constants: B=32, H=W=64, C=256, heads=8, ws=8, ss=4
#define MROWS 131072   // B * 64 * 64 tokens

__device__ __forceinline__ bf16_t to_bf16(float f) {
  __hip_bfloat16 h = __float2bfloat16(f);   // RNE
  return *reinterpret_cast<bf16_t*>(&h);
}

__device__ __forceinline__ f32x4 mfma16(bf16x8 a, bf16x8 b, f32x4 c) {
  return __builtin_amdgcn_mfma_f32_16x16x32_bf16(a, b, c, 0, 0, 0);
}

__device__ __forceinline__ void gload16(const void* g, void* l) {
  __builtin_amdgcn_global_load_lds(
      (const __attribute__((address_space(1))) void*)g,
      (__attribute__((address_space(3))) void*)l, 16, 0, 0);
}

// window-layout row m  ->  x row (shift+partition gather; reverse+unshift scatter)
__device__ __forceinline__ int map_row(int m) {
  int b   = m >> 12;
  int rem = m & 4095;
  int win = rem >> 6;
  int n   = rem & 63;
  int gh  = ((win >> 3) << 3) + (n >> 3);
  int gw  = ((win & 7) << 3) + (n & 7);
  int sh  = (gh + 4) & 63;
  int sw  = (gw + 4) & 63;
  return (b << 12) + (sh << 6) + sw;
}

// ---------------- fp32 -> bf16 weight convert ----------------
__global__ __launch_bounds__(256) void cvt_kernel(const float* __restrict__ in,
                                                  bf16_t* __restrict__ out, int n) {
  int i = blockIdx.x * 256 + threadIdx.x;
  if (i < n) out[i] = to_bf16(in[i]);
}

// ---------------- bias table: bias[cls][h][n][m] = rpb(n,m,h) + mask(cls,n,m) ----------------
__global__ __launch_bounds__(256) void bias_kernel(const float* __restrict__ rpbt,
                                                   float* __restrict__ bias) {
  int idx = blockIdx.x * 256 + threadIdx.x;   // 0 .. 131071
  int m = idx & 63, n = (idx >> 6) & 63, h = (idx >> 12) & 7, c = idx >> 15;
  int yn = n >> 3, xn = n & 7, ym = m >> 3, xm = m & 7;
  float v = rpbt[((yn - ym + 7) * 15 + (xn - xm + 7)) * 8 + h];
  int rn = (c & 2) ? (yn < 4 ? 1 : 2) : 0;
  int cn = (c & 1) ? (xn < 4 ? 1 : 2) : 0;
  int rm = (c & 2) ? (ym < 4 ? 1 : 2) : 0;
  int cm = (c & 1) ? (xm < 4 ? 1 : 2) : 0;
  if (rn * 3 + cn != rm * 3 + cm) v -= 100.0f;
  bias[idx] = v;
}

// ---------------- LayerNorm (wave per row) fp32 -> bf16 ----------------
__global__ __launch_bounds__(256) void ln_kernel(const float* __restrict__ xin,
                                                 const float* __restrict__ g,
                                                 const float* __restrict__ b,
                                                 bf16_t* __restrict__ out) {
  int row  = (blockIdx.x << 2) + (threadIdx.x >> 6);
  int lane = threadIdx.x & 63;
  float4 v = *reinterpret_cast<const float4*>(xin + (size_t)row * 256 + (lane << 2));
  float s = v.x + v.y + v.z + v.w;
#pragma unroll
  for (int d = 1; d < 64; d <<= 1) s += __shfl_xor(s, d);
  float mean = s * 0.00390625f;
  float ax = v.x - mean, ay = v.y - mean, az = v.z - mean, aw = v.w - mean;
  float s2 = ax * ax + ay * ay + az * az + aw * aw;
#pragma unroll
  for (int d = 1; d < 64; d <<= 1) s2 += __shfl_xor(s2, d);
  float rstd = rsqrtf(s2 * 0.00390625f + 1e-5f);
  float4 gv = *reinterpret_cast<const float4*>(g + (lane << 2));
  float4 bv = *reinterpret_cast<const float4*>(b + (lane << 2));
  typedef __bf16 bf16x4 __attribute__((ext_vector_type(4)));
  bf16x4 o4;
  o4[0] = to_bf16(ax * rstd * gv.x + bv.x);
  o4[1] = to_bf16(ay * rstd * gv.y + bv.y);
  o4[2] = to_bf16(az * rstd * gv.z + bv.z);
  o4[3] = to_bf16(aw * rstd * gv.w + bv.w);
  *reinterpret_cast<bf16x4*>(out + (size_t)row * 256 + (lane << 2)) = o4;
}

// ---------------- bf16 GEMM, B^T weights (m97 structure), grid: x=bn (fast), y=bm
// EPI 1: GELU(exact) then bf16     EPI 3: fp32 in-place += (stride 256)
template <int EPI>
__global__ __launch_bounds__(256) void gemm_bt(const bf16_t* __restrict__ A,
                                               const bf16_t* __restrict__ W,
                                               const float* __restrict__ bias,
                                               void* __restrict__ outp,
                                               int M, int N, int K) {
  __shared__ __align__(16) bf16_t As[128 * 32];
  __shared__ __align__(16) bf16_t Bs[128 * 32];
  const int tid  = threadIdx.x;
  const int lane = tid & 63, lo = lane & 15, hi = lane >> 4;
  const int wave = tid >> 6;
  const int bm = blockIdx.y << 7, bn = blockIdx.x << 7;   // bn fastest -> A-tile L3-hot
  const int wr = (wave >> 1) << 6, wc = (wave & 1) << 6;
  f32x4 acc[4][4] = {};

  for (int k0 = 0; k0 < K; k0 += 32) {
    __syncthreads();
#pragma unroll
    for (int it = 0; it < 2; ++it) {
      int ch = (it << 8) + tid;
      int r = ch >> 2, kf = (ch & 3) << 3;
      gload16(A + (size_t)(bm + r) * K + (k0 + kf), &As[ch << 3]);
      gload16(W + (size_t)(bn + r) * K + (k0 + kf), &Bs[ch << 3]);
    }
    __syncthreads();
    bf16x8 af[4], bfr[4];
#pragma unroll
    for (int i = 0; i < 4; ++i)
      af[i] = *reinterpret_cast<const bf16x8*>(&As[(wr + (i << 4) + lo) * 32 + (hi << 3)]);
#pragma unroll
    for (int j = 0; j < 4; ++j)
      bfr[j] = *reinterpret_cast<const bf16x8*>(&Bs[(wc + (j << 4) + lo) * 32 + (hi << 3)]);
#pragma unroll
    for (int i = 0; i < 4; ++i)
#pragma unroll
      for (int j = 0; j < 4; ++j)
        acc[i][j] = mfma16(af[i], bfr[j], acc[i][j]);
  }

  float bv[4];
#pragma unroll
  for (int j = 0; j < 4; ++j) bv[j] = bias[bn + wc + (j << 4) + lo];

#pragma unroll
  for (int i = 0; i < 4; ++i) {
#pragma unroll
    for (int r = 0; r < 4; ++r) {
      int row = bm + wr + (i << 4) + (hi << 2) + r;
      if constexpr (EPI == 3) {
        float* o = (float*)outp;
#pragma unroll
        for (int j = 0; j < 4; ++j) {
          int col = bn + wc + (j << 4) + lo;
          size_t idx = (size_t)row * 256 + col;
          o[idx] = o[idx] + acc[i][j][r] + bv[j];
        }
      } else {
        bf16_t* o = (bf16_t*)outp;
#pragma unroll
        for (int j = 0; j < 4; ++j) {
          int col = bn + wc + (j << 4) + lo;
          float v = acc[i][j][r] + bv[j];
          if constexpr (EPI == 1) v = 0.5f * v * (1.0f + erff(v * 0.70710678118654752f));
          o[(size_t)row * N + col] = to_bf16(v);
        }
      }
    }
  }
}

// ---------------- mega: LN1+shift+QKV+attention+proj+residual, one block per window ----
// 1024 threads = 16 waves; head h owned by wave pair (2h, 2h+1).
//   P1 (QKV GEMM) split by d-half   (wave sub = w&1 computes 16 of 32 channels)
//   attention     split by n-half   (wave sub computes 32 of 64 rows)
// LDS 152576 B: A_lds [64][264] bf16 (33792 B, O_lds overlays after P1)
//   per-head 14848 B: q[64][40] | k[64][40] | Vt[32][72];  P[64][72] overlays q+k
__global__ __launch_bounds__(1024, 4) void mega_attn(
    const float* __restrict__ x, const float* __restrict__ n1g,
    const float* __restrict__ n1b, const bf16_t* __restrict__ qkv_wb,
    const float* __restrict__ qkv_b, const bf16_t* __restrict__ proj_wb,
    const float* __restrict__ proj_b, const float* __restrict__ bias,
    float* __restrict__ out) {
  extern __shared__ __align__(16) char smem_raw[];
  bf16_t* Sm = (bf16_t*)smem_raw;
  bf16_t* A_lds = Sm;                       // [64][264] el (O_lds later)
  const int tid = threadIdx.x;
  const int lane = tid & 63, lo = lane & 15, hi = lane >> 4;
  const int wave = tid >> 6;                // 0..15
  const int h = wave >> 1, sub = wave & 1;
  const int win = blockIdx.x;               // 0..2047
  bf16_t* Wv    = Sm + 16896 + h * 7424;
  bf16_t* q_lds = Wv;                       // [64][40]
  bf16_t* k_lds = Wv + 2560;                // [64][40]
  bf16_t* Vt    = Wv + 5120;                // [32][72]
  bf16_t* Pl    = Wv;                       // [64][72] overlays q+k

  // ---- P0: LN1 + shifted-window gather -> A_lds (16 threads per row) ----
  {
    const int row = tid >> 4, s = tid & 15;
    const int src = map_row((win << 6) + row);
    const float* xp = x + (size_t)src * 256 + (s << 4);
    float f[16];
#pragma unroll
    for (int c = 0; c < 4; ++c) {
      float4 v = *reinterpret_cast<const float4*>(xp + (c << 2));
      f[c * 4 + 0] = v.x; f[c * 4 + 1] = v.y; f[c * 4 + 2] = v.z; f[c * 4 + 3] = v.w;
    }
    float sum = 0.0f;
#pragma unroll
    for (int e = 0; e < 16; ++e) sum += f[e];
#pragma unroll
    for (int d = 1; d < 16; d <<= 1) sum += __shfl_xor(sum, d);
    float mean = sum * 0.00390625f;
    float var = 0.0f;
#pragma unroll
    for (int e = 0; e < 16; ++e) { float t = f[e] - mean; var += t * t; }
#pragma unroll
    for (int d = 1; d < 16; d <<= 1) var += __shfl_xor(var, d);
    float rstd = rsqrtf(var * 0.00390625f + 1e-5f);
    const float* gp = n1g + (s << 4);
    const float* bp = n1b + (s << 4);
#pragma unroll
    for (int c = 0; c < 2; ++c) {
      bf16x8 w;
#pragma unroll
      for (int e = 0; e < 8; ++e) {
        int idx = (c << 3) + e;
        w[e] = to_bf16((f[idx] - mean) * rstd * gp[idx] + bp[idx]);
      }
      *reinterpret_cast<bf16x8*>(&A_lds[row * 264 + (s << 4) + (c << 3)]) = w;
    }
  }
  __syncthreads();   // B1: A ready

  // ---- P1: QKV (d-split): wave computes its head's 16 channels for all 64 tokens ----
  // acc[j] holds X@W^T [n=j*16+lo][d = sub*16 + hi*4 + r]
  f32x4 aq[4] = {}, ak[4] = {}, av[4] = {};
  {
    const int drow = h * 32 + sub * 16 + lo;
#pragma unroll 2
    for (int kk = 0; kk < 8; ++kk) {
      const int k0 = kk << 5;
      bf16x8 fb[4];
#pragma unroll
      for (int j = 0; j < 4; ++j)
        fb[j] = *reinterpret_cast<const bf16x8*>(&A_lds[((j << 4) + lo) * 264 + k0 + (hi << 3)]);
      bf16x8 wfq = *reinterpret_cast<const bf16x8*>(qkv_wb + (size_t)(drow      ) * 256 + k0 + (hi << 3));
      bf16x8 wfk = *reinterpret_cast<const bf16x8*>(qkv_wb + (size_t)(drow + 256) * 256 + k0 + (hi << 3));
      bf16x8 wfv = *reinterpret_cast<const bf16x8*>(qkv_wb + (size_t)(drow + 512) * 256 + k0 + (hi << 3));
#pragma unroll
      for (int j = 0; j < 4; ++j) {
        aq[j] = mfma16(wfq, fb[j], aq[j]);
        ak[j] = mfma16(wfk, fb[j], ak[j]);
        av[j] = mfma16(wfv, fb[j], av[j]);
      }
    }
  }

  // ---- P2: dump q,k,Vt into per-head LDS (+bias) ----
#pragma unroll
  for (int r = 0; r < 4; ++r) {
    int d = sub * 16 + (hi << 2) + r;      // 0..31 within head
    float bq = qkv_b[h * 32 + d];
    float bk = qkv_b[256 + h * 32 + d];
    float bv = qkv_b[512 + h * 32 + d];
#pragma unroll
    for (int j = 0; j < 4; ++j) {
      int n = (j << 4) + lo;
      q_lds[n * 40 + d] = to_bf16(aq[j][r] + bq);
      k_lds[n * 40 + d] = to_bf16(ak[j][r] + bk);
      Vt[d * 72 + n]    = to_bf16(av[j][r] + bv);
    }
  }
  __syncthreads();   // B2: pair's q/k/Vt complete (also: A dead from here)

  // ---- P3: QK^T (n-split): wave computes rows n = sub*32 .. sub*32+31 ----
  bf16x8 qa[2], ka[4];
#pragma unroll
  for (int il = 0; il < 2; ++il)
    qa[il] = *reinterpret_cast<const bf16x8*>(&q_lds[(sub * 32 + (il << 4) + lo) * 40 + (hi << 3)]);
#pragma unroll
  for (int j = 0; j < 4; ++j)
    ka[j] = *reinterpret_cast<const bf16x8*>(&k_lds[((j << 4) + lo) * 40 + (hi << 3)]);
  f32x4 s4[2][4] = {};
#pragma unroll
  for (int il = 0; il < 2; ++il)
#pragma unroll
    for (int j = 0; j < 4; ++j) s4[il][j] = mfma16(qa[il], ka[j], s4[il][j]);

  __syncthreads();   // B3: both waves done reading q/k before P overlays them

  // ---- P3b: softmax rows (own 32), write P ----
  const int wh = (win & 63) >> 3, ww = win & 7;
  const int cls = ((wh == 7) ? 2 : 0) + ((ww == 7) ? 1 : 0);
  const float* bb = bias + ((size_t)cls * 8 + h) * 4096;
  const float scale = 0.17677669529663687f;  // 1/sqrt(32)

  float pinv[2][4];
#pragma unroll
  for (int il = 0; il < 2; ++il) {
#pragma unroll
    for (int r = 0; r < 4; ++r) {
      int n = sub * 32 + (il << 4) + (hi << 2) + r;
      const float* brow = bb + n * 64 + lo;
      float vals[4], mx = -1e30f;
#pragma unroll
      for (int j = 0; j < 4; ++j) {
        float val = s4[il][j][r] * scale + brow[j << 4];
        vals[j] = val;
        mx = fmaxf(mx, val);
      }
#pragma unroll
      for (int d = 1; d < 16; d <<= 1) mx = fmaxf(mx, __shfl_xor(mx, d));
      float sum = 0.0f;
#pragma unroll
      for (int j = 0; j < 4; ++j) {
        float p = __expf(vals[j] - mx);
        sum += p;
        Pl[n * 72 + (j << 4) + lo] = to_bf16(p);
      }
#pragma unroll
      for (int d = 1; d < 16; d <<= 1) sum += __shfl_xor(sum, d);
      pinv[il][r] = 1.0f / sum;
    }
  }

  // ---- PV: O[own 32, 32] = P[own 32, 64] @ V[64, 32] ----
  f32x4 oa[2][2] = {};
#pragma unroll
  for (int kt = 0; kt < 2; ++kt) {
    bf16x8 pa[2], va[2];
#pragma unroll
    for (int il = 0; il < 2; ++il)
      pa[il] = *reinterpret_cast<const bf16x8*>(&Pl[(sub * 32 + (il << 4) + lo) * 72 + (kt << 5) + (hi << 3)]);
#pragma unroll
    for (int dt = 0; dt < 2; ++dt)
      va[dt] = *reinterpret_cast<const bf16x8*>(&Vt[((dt << 4) + lo) * 72 + (kt << 5) + (hi << 3)]);
#pragma unroll
    for (int il = 0; il < 2; ++il)
#pragma unroll
      for (int dt = 0; dt < 2; ++dt) oa[il][dt] = mfma16(pa[il], va[dt], oa[il][dt]);
  }

  // ---- P4: O -> O_lds (overlays A; all waves past B2/B3, A dead) ----
#pragma unroll
  for (int il = 0; il < 2; ++il)
#pragma unroll
    for (int r = 0; r < 4; ++r) {
      int n = sub * 32 + (il << 4) + (hi << 2) + r;
      float piv = pinv[il][r];
#pragma unroll
      for (int dt = 0; dt < 2; ++dt)
        A_lds[n * 264 + h * 32 + (dt << 4) + lo] = to_bf16(oa[il][dt][r] * piv);
    }
  __syncthreads();   // B4: O complete

  // ---- P5: proj (wave owns 16 out-cols) + reverse-scatter + residual -> fp32 out ----
  {
    const int c0 = wave << 4;
    f32x4 ap[4] = {};
#pragma unroll 2
    for (int kk = 0; kk < 8; ++kk) {
      const int k0 = kk << 5;
      bf16x8 fa[4];
#pragma unroll
      for (int i = 0; i < 4; ++i)
        fa[i] = *reinterpret_cast<const bf16x8*>(&A_lds[((i << 4) + lo) * 264 + k0 + (hi << 3)]);
      bf16x8 wp = *reinterpret_cast<const bf16x8*>(proj_wb + (size_t)(c0 + lo) * 256 + k0 + (hi << 3));
#pragma unroll
      for (int i = 0; i < 4; ++i) ap[i] = mfma16(fa[i], wp, ap[i]);
    }
    float pb = proj_b[c0 + lo];
#pragma unroll
    for (int i = 0; i < 4; ++i)
#pragma unroll
      for (int r = 0; r < 4; ++r) {
        int m = (i << 4) + (hi << 2) + r;
        int xr = map_row((win << 6) + m);
        size_t idx = (size_t)xr * 256 + c0 + lo;
        out[idx] = x[idx] + ap[i][r] + pb;
      }
  }
}

// ---------------- launch ----------------
extern "C" void kernel_launch(void* const* d_in, const int* in_sizes, int n_in,
                              void* d_out, int out_size, void* d_ws, size_t ws_size,
                              hipStream_t stream) {
  const float* x      = (const float*)d_in[0];
  const float* n1g    = (const float*)d_in[1];
  const float* n1b    = (const float*)d_in[2];
  const float* qkv_w  = (const float*)d_in[3];
  const float* qkv_b  = (const float*)d_in[4];
  const float* rpbt   = (const float*)d_in[5];
  const float* proj_w = (const float*)d_in[6];
  const float* proj_b = (const float*)d_in[7];
  const float* n2g    = (const float*)d_in[8];
  const float* n2b    = (const float*)d_in[9];
  const float* fc1_w  = (const float*)d_in[10];
  const float* fc1_b  = (const float*)d_in[11];
  const float* fc2_w  = (const float*)d_in[12];
  const float* fc2_b  = (const float*)d_in[13];
  float* out = (float*)d_out;
  char*  ws  = (char*)d_ws;

  // ws: [0,64MB) h2 chunk | [64,128MB) x2n | [128MB..] bf16 weights + bias table
  const size_t MB64 = 67108864;
  bf16_t* h2   = (bf16_t*)(ws);
  bf16_t* x2n  = (bf16_t*)(ws + MB64);
  bf16_t* wb   = (bf16_t*)(ws + 2 * MB64);
  bf16_t* qkv_wb  = wb;                   // 196608 el
  bf16_t* proj_wb = qkv_wb + 196608;      // 65536
  bf16_t* fc1_wb  = proj_wb + 65536;      // 262144
  bf16_t* fc2_wb  = fc1_wb + 262144;      // 262144
  float*  biast   = (float*)(fc2_wb + 262144);  // 131072 f32 = 512KB

  static const int MEGA_LDS = 152576;
  hipFuncSetAttribute(reinterpret_cast<const void*>(mega_attn),
                      hipFuncAttributeMaxDynamicSharedMemorySize, MEGA_LDS);

  cvt_kernel<<<768, 256, 0, stream>>>(qkv_w, qkv_wb, 196608);
  cvt_kernel<<<256, 256, 0, stream>>>(proj_w, proj_wb, 65536);
  cvt_kernel<<<1024, 256, 0, stream>>>(fc1_w, fc1_wb, 262144);
  cvt_kernel<<<1024, 256, 0, stream>>>(fc2_w, fc2_wb, 262144);
  bias_kernel<<<512, 256, 0, stream>>>(rpbt, biast);

  // LN1 + shift + QKV + attention + proj + residual -> x2 fp32 in d_out
  mega_attn<<<2048, 1024, MEGA_LDS, stream>>>(x, n1g, n1b, qkv_wb, qkv_b,
                                              proj_wb, proj_b, biast, out);

  // LN2
  ln_kernel<<<32768, 256, 0, stream>>>(out, n2g, n2b, x2n);

  // MLP in 4 row-chunks (h2 chunk = 32768 x 1024 bf16 = 64MB)
  for (int c = 0; c < 4; ++c) {
    const bf16_t* xa = x2n + (size_t)c * 32768 * 256;
    gemm_bt<1><<<dim3(8, 256), 256, 0, stream>>>(xa, fc1_wb, fc1_b, h2, 32768, 1024, 256);
    gemm_bt<3><<<dim3(2, 256), 256, 0, stream>>>(h2, fc2_wb, fc2_b, out + (size_t)c * 32768 * 256,
                                                 32768, 256, 1024);
  }
}